// Round 4
// baseline (187.985 us; speedup 1.0000x reference)
//
#include <hip/hip_runtime.h>
#include <hip/hip_cooperative_groups.h>
#include <math.h>

namespace cg = cooperative_groups;

#define BQ 256   // batch
#define NXQ 256  // spatial points
#define TQ 100   // time steps
#define N2 512   // 2*B
#define TILE 32
#define PITCH 257  // 257 % 32 == 1 -> conflict-free row access

// ---------------------------------------------------------------------------
// Single cooperative kernel, 4 phases over 256 blocks (1/CU, co-resident):
//   P: prep   — block g computes A/C rows g and g+256 (R2-proven body)
//   D: dist   — block g computes SIM tile (g>>4, g&15)  (R2-proven body)
//   R: row    — block g computes ROW[g] and ROW[g+256]  (R2-proven body)
//   F: final  — block 0 reduces ROW -> out              (R2-proven body)
// grid.sync() between phases (device-scope fence + barrier). All arithmetic
// is byte-identical to the verified 4-launch version -> absmax 0.0.
// ---------------------------------------------------------------------------
__global__ __launch_bounds__(256) void fused_all(
    const float* __restrict__ x1, const float* __restrict__ x2,
    const float* __restrict__ u, const float* __restrict__ dt,
    const float* __restrict__ dx, const float* __restrict__ vs,
    float* __restrict__ A, float* __restrict__ C,
    float* __restrict__ SIM, double* __restrict__ ROW,
    float* __restrict__ out) {
  cg::grid_group grid = cg::this_grid();
  __shared__ float At[TILE * PITCH];
  __shared__ float Ct[TILE * PITCH];
  __shared__ float wmax[4];
  __shared__ double wsum[4];
  int g = blockIdx.x;
  int t = threadIdx.x;

  // ---------------- phase P: prep (b = g) ----------------
  {
    float* w2s = At;  // reuse LDS as scratch (256 floats each)
    float* w1s = Ct;
    int b = g;
    float w2 = x2[b * NXQ + t];  // reps row b      (r < B  -> x2)
    float w1 = x1[b * NXQ + t];  // reps row b+256  (r >= B -> x1)
    w2s[t] = w2;
    w1s[t] = w1;
    float2 uv = *(const float2*)(u + (size_t)(b * NXQ + t) * TQ + (TQ - 2));
    float dtv = dt[b];
    float dxv = dx[0];
    float c0 = vs[b * 3 + 0], c1 = vs[b * 3 + 1], c2 = vs[b * 3 + 2];
    __syncthreads();
    int tm = (t + NXQ - 1) & (NXQ - 1);
    int tp = (t + 1) & (NXQ - 1);
    float w2m = w2s[tm], w2p = w2s[tp];
    float w1m = w1s[tm], w1p = w1s[tp];
    float adv2 = c0 * dtv * (w2m - w2p) * w2 / (2.0f * dxv);
    float dif2 = -(c1 * dtv * (w2m + w2p - 2.0f * w2) / (dxv * dxv));
    float dis2 = -c2 * dtv * (w2 - w2p) / dxv;
    float adv1 = c0 * dtv * (w1m - w1p) * w1 / (2.0f * dxv);
    float dif1 = -(c1 * dtv * (w1m + w1p - 2.0f * w1) / (dxv * dxv));
    float dis1 = -c2 * dtv * (w1 - w1p) / dxv;
    A[b * NXQ + t] = uv.y + w2;
    A[(b + BQ) * NXQ + t] = uv.y + w1;
    C[b * NXQ + t] = uv.x + w2 + (adv2 + dif2 + dis2);
    C[(b + BQ) * NXQ + t] = uv.x + w1 + (adv1 + dif1 + dis1);
  }
  grid.sync();

  // ---------------- phase D: dist (tile g>>4, g&15) ----------------
  {
    int i0 = (g >> 4) * TILE;
    int j0 = (g & 15) * TILE;
    for (int k = 0; k < TILE * NXQ / 256; k++) {
      int idx = k * 256 + t;
      int row = idx >> 8;
      int col = idx & (NXQ - 1);
      At[row * PITCH + col] = A[(j0 + row) * NXQ + col];
      Ct[row * PITCH + col] = C[(i0 + row) * NXQ + col];
    }
    __syncthreads();
    int ii = t >> 3;         // 0..31
    int jj = (t & 7) << 2;   // 0,4,...,28 -> 4 outputs each
    float acc0 = 0.f, acc1 = 0.f, acc2 = 0.f, acc3 = 0.f;
    for (int x = 0; x < NXQ; x++) {
      float cv = Ct[ii * PITCH + x];
      float d0 = At[(jj + 0) * PITCH + x] - cv;
      float d1 = At[(jj + 1) * PITCH + x] - cv;
      float d2 = At[(jj + 2) * PITCH + x] - cv;
      float d3 = At[(jj + 3) * PITCH + x] - cv;
      acc0 = fmaf(d0, d0, acc0);
      acc1 = fmaf(d1, d1, acc1);
      acc2 = fmaf(d2, d2, acc2);
      acc3 = fmaf(d3, d3, acc3);
    }
    float4 v = make_float4(acc0, acc1, acc2, acc3);
    *(float4*)&SIM[(i0 + ii) * N2 + j0 + jj] = v;
  }
  grid.sync();

  // ---------------- phase R: rows g and g+256 ----------------
  for (int rr = 0; rr < 2; rr++) {
    int r = g + rr * BQ;
    int rb = r & (BQ - 1);
    float vi0 = vs[rb * 3], vi1 = vs[rb * 3 + 1], vi2 = vs[rb * 3 + 2];
    float vj0 = vs[t * 3], vj1 = vs[t * 3 + 1], vj2 = vs[t * 3 + 2];
    float nvi = sqrtf(vi0 * vi0 + vi1 * vi1 + vi2 * vi2);
    float nvj = sqrtf(vj0 * vj0 + vj1 * vj1 + vj2 * vj2);
    float prod = sqrtf(fabsf(vi0 * vj0) + fabsf(vi1 * vj1) + fabsf(vi2 * vj2));
    float sim = prod / fmaxf(nvi, nvj);
    float ssv = 1.0f - 0.9f * sim;
    if (isnan(ssv)) ssv = 0.0f;

    int jstar = (r + BQ) & (N2 - 1);  // positive column
    float posval = SIM[r * N2 + jstar];
    float v0, v1;
    {
      int j = t;
      if (j == jstar)                v0 = posval;
      else if ((j & (BQ - 1)) == rb) v0 = -INFINITY;  // excluded (j == r)
      else                           v0 = SIM[r * N2 + j] * ssv;
    }
    {
      int j = t + BQ;
      if (j == jstar)                v1 = posval;
      else if ((j & (BQ - 1)) == rb) v1 = -INFINITY;  // excluded
      else                           v1 = SIM[r * N2 + j] * ssv;
    }
    float m = fmaxf(v0, v1);
    for (int off = 32; off > 0; off >>= 1) m = fmaxf(m, __shfl_down(m, off, 64));
    int wave = t >> 6, lane = t & 63;
    if (lane == 0) wmax[wave] = m;
    __syncthreads();
    float M = fmaxf(fmaxf(wmax[0], wmax[1]), fmaxf(wmax[2], wmax[3]));
    double s = 0.0;
    if (v0 != -INFINITY) s += exp((double)(v0 - M));
    if (v1 != -INFINITY) s += exp((double)(v1 - M));
    for (int off = 32; off > 0; off >>= 1) s += __shfl_down(s, off, 64);
    if (lane == 0) wsum[wave] = s;
    __syncthreads();
    if (t == 0) {
      double S = wsum[0] + wsum[1] + wsum[2] + wsum[3];
      ROW[r] = (double)M + log(S) - (double)posval;
    }
    __syncthreads();  // protect wmax/wsum reuse in next iteration
  }
  grid.sync();

  // ---------------- phase F: final reduce (block 0) ----------------
  if (g == 0) {
    double s = ROW[t] + ROW[t + 256];
    for (int off = 32; off > 0; off >>= 1) s += __shfl_down(s, off, 64);
    int wave = t >> 6, lane = t & 63;
    if (lane == 0) wsum[wave] = s;
    __syncthreads();
    if (t == 0) {
      double S = wsum[0] + wsum[1] + wsum[2] + wsum[3];
      out[0] = (float)(S / (double)N2);
    }
  }
}

extern "C" void kernel_launch(void* const* d_in, const int* in_sizes, int n_in,
                              void* d_out, int out_size, void* d_ws, size_t ws_size,
                              hipStream_t stream) {
  const float* x1 = (const float*)d_in[0];  // [B, NX, 1, 1]
  const float* x2 = (const float*)d_in[1];  // [B, NX, 1, 1]
  const float* u  = (const float*)d_in[2];  // [B, NX, T]
  const float* dt = (const float*)d_in[3];  // [B]
  const float* dx = (const float*)d_in[4];  // [1]
  const float* vs = (const float*)d_in[5];  // [B, 3]
  char* ws = (char*)d_ws;
  float*  SIM = (float*)(ws + 0);          // 512*512*4 = 1 MB
  float*  A   = (float*)(ws + 1048576);    // 512*256*4 = 512 KB
  float*  C   = (float*)(ws + 1572864);    // 512 KB
  double* ROW = (double*)(ws + 2097152);   // 512*8 = 4 KB
  float* out = (float*)d_out;

  void* args[] = {(void*)&x1, (void*)&x2, (void*)&u,   (void*)&dt,
                  (void*)&dx, (void*)&vs, (void*)&A,   (void*)&C,
                  (void*)&SIM, (void*)&ROW, (void*)&out};
  hipLaunchCooperativeKernel((const void*)fused_all, dim3(BQ), dim3(256), args, 0,
                             stream);
}

// Round 5
// 93.123 us; speedup vs baseline: 2.0187x; 2.0187x over previous
//
#include <hip/hip_runtime.h>
#include <math.h>

#define BQ 256   // batch
#define NXQ 256  // spatial points
#define TQ 100   // time steps
#define N2 512   // 2*B
#define TILE 32
#define PITCH 257  // 257 % 32 == 1 -> conflict-free row access

// ---------------------------------------------------------------------------
// K1: prep — for each b in [0,256): rows r=b (x2) and r=b+256 (x1).
//     A[r][x] = u[b,x,T-1] + rep[r,x]
//     C[r][x] = u[b,x,T-2] + rep[r,x] + upd(rep,dt,vs,dx)[x]
//     u pair gathered ONCE per (b,x) as an aligned float2 (offsets 98,99).
// ---------------------------------------------------------------------------
__global__ __launch_bounds__(256) void prep_kernel(
    const float* __restrict__ x1, const float* __restrict__ x2,
    const float* __restrict__ u, const float* __restrict__ dt,
    const float* __restrict__ dx, const float* __restrict__ vs,
    float* __restrict__ A, float* __restrict__ C) {
  int b = blockIdx.x;
  int t = threadIdx.x;
  __shared__ float w2s[NXQ], w1s[NXQ];
  float w2 = x2[b * NXQ + t];  // reps row b      (r < B  -> x2)
  float w1 = x1[b * NXQ + t];  // reps row b+256  (r >= B -> x1)
  w2s[t] = w2;
  w1s[t] = w1;
  // u[b, x=t, 98] and u[b, x=t, 99]: byte offset ((b*256+t)*100+98)*4 is 8-aligned
  float2 uv = *(const float2*)(u + (size_t)(b * NXQ + t) * TQ + (TQ - 2));
  float dtv = dt[b];
  float dxv = dx[0];
  float c0 = vs[b * 3 + 0], c1 = vs[b * 3 + 1], c2 = vs[b * 3 + 2];
  __syncthreads();
  int tm = (t + NXQ - 1) & (NXQ - 1);
  int tp = (t + 1) & (NXQ - 1);
  float w2m = w2s[tm], w2p = w2s[tp];
  float w1m = w1s[tm], w1p = w1s[tp];
  // keep the exact expression forms of the verified kernel (division, not rcp)
  float adv2 = c0 * dtv * (w2m - w2p) * w2 / (2.0f * dxv);
  float dif2 = -(c1 * dtv * (w2m + w2p - 2.0f * w2) / (dxv * dxv));
  float dis2 = -c2 * dtv * (w2 - w2p) / dxv;
  float adv1 = c0 * dtv * (w1m - w1p) * w1 / (2.0f * dxv);
  float dif1 = -(c1 * dtv * (w1m + w1p - 2.0f * w1) / (dxv * dxv));
  float dis1 = -c2 * dtv * (w1 - w1p) / dxv;
  A[b * NXQ + t] = uv.y + w2;
  A[(b + BQ) * NXQ + t] = uv.y + w1;
  C[b * NXQ + t] = uv.x + w2 + (adv2 + dif2 + dis2);
  C[(b + BQ) * NXQ + t] = uv.x + w1 + (adv1 + dif1 + dis1);
}

// ---------------------------------------------------------------------------
// K2: SIM[i][j] = sum_x (A[j][x] - C[i][x])^2 ; 32x32 tile per block,
//     full K=256 staged in LDS (2 * 32 * 257 * 4B = 65.8 KB)
//     [proven version — unchanged]
// ---------------------------------------------------------------------------
__global__ __launch_bounds__(256) void dist_kernel(const float* __restrict__ A,
                                                   const float* __restrict__ C,
                                                   float* __restrict__ SIM) {
  __shared__ float At[TILE * PITCH];
  __shared__ float Ct[TILE * PITCH];
  int t = threadIdx.x;
  int i0 = blockIdx.y * TILE;
  int j0 = blockIdx.x * TILE;
  for (int k = 0; k < TILE * NXQ / 256; k++) {
    int idx = k * 256 + t;
    int row = idx >> 8;
    int col = idx & (NXQ - 1);
    At[row * PITCH + col] = A[(j0 + row) * NXQ + col];
    Ct[row * PITCH + col] = C[(i0 + row) * NXQ + col];
  }
  __syncthreads();
  int ii = t >> 3;         // 0..31
  int jj = (t & 7) << 2;   // 0,4,...,28 -> 4 outputs each
  float acc0 = 0.f, acc1 = 0.f, acc2 = 0.f, acc3 = 0.f;
  for (int x = 0; x < NXQ; x++) {
    float cv = Ct[ii * PITCH + x];
    float d0 = At[(jj + 0) * PITCH + x] - cv;
    float d1 = At[(jj + 1) * PITCH + x] - cv;
    float d2 = At[(jj + 2) * PITCH + x] - cv;
    float d3 = At[(jj + 3) * PITCH + x] - cv;
    acc0 = fmaf(d0, d0, acc0);
    acc1 = fmaf(d1, d1, acc1);
    acc2 = fmaf(d2, d2, acc2);
    acc3 = fmaf(d3, d3, acc3);
  }
  float4 v = make_float4(acc0, acc1, acc2, acc3);
  *(float4*)&SIM[(i0 + ii) * N2 + j0 + jj] = v;
}

// ---------------------------------------------------------------------------
// K3: per-row logsumexp over [pos] + weighted negatives; SS computed inline
//     from vs (3 KB, L1-resident). ROW[r] = lse - pos.
// ---------------------------------------------------------------------------
__global__ __launch_bounds__(256) void row_kernel(const float* __restrict__ SIM,
                                                  const float* __restrict__ vs,
                                                  double* __restrict__ ROW) {
  int r = blockIdx.x;
  int t = threadIdx.x;
  int rb = r & (BQ - 1);
  float vi0 = vs[rb * 3], vi1 = vs[rb * 3 + 1], vi2 = vs[rb * 3 + 2];
  float vj0 = vs[t * 3], vj1 = vs[t * 3 + 1], vj2 = vs[t * 3 + 2];
  float nvi = sqrtf(vi0 * vi0 + vi1 * vi1 + vi2 * vi2);
  float nvj = sqrtf(vj0 * vj0 + vj1 * vj1 + vj2 * vj2);
  float prod = sqrtf(fabsf(vi0 * vj0) + fabsf(vi1 * vj1) + fabsf(vi2 * vj2));
  float sim = prod / fmaxf(nvi, nvj);
  float ssv = 1.0f - 0.9f * sim;
  if (isnan(ssv)) ssv = 0.0f;

  int jstar = (r + BQ) & (N2 - 1);  // positive column
  float posval = SIM[r * N2 + jstar];
  float v0, v1;
  {
    int j = t;
    if (j == jstar)                v0 = posval;
    else if ((j & (BQ - 1)) == rb) v0 = -INFINITY;  // excluded (j == r)
    else                           v0 = SIM[r * N2 + j] * ssv;
  }
  {
    int j = t + BQ;
    if (j == jstar)                v1 = posval;
    else if ((j & (BQ - 1)) == rb) v1 = -INFINITY;  // excluded
    else                           v1 = SIM[r * N2 + j] * ssv;
  }
  float m = fmaxf(v0, v1);
  for (int off = 32; off > 0; off >>= 1) m = fmaxf(m, __shfl_down(m, off, 64));
  __shared__ float wmax[4];
  __shared__ double wsum[4];
  int wave = t >> 6, lane = t & 63;
  if (lane == 0) wmax[wave] = m;
  __syncthreads();
  float M = fmaxf(fmaxf(wmax[0], wmax[1]), fmaxf(wmax[2], wmax[3]));
  double s = 0.0;
  if (v0 != -INFINITY) s += exp((double)(v0 - M));
  if (v1 != -INFINITY) s += exp((double)(v1 - M));
  for (int off = 32; off > 0; off >>= 1) s += __shfl_down(s, off, 64);
  if (lane == 0) wsum[wave] = s;
  __syncthreads();
  if (t == 0) {
    double S = wsum[0] + wsum[1] + wsum[2] + wsum[3];
    ROW[r] = (double)M + log(S) - (double)posval;
  }
}

// ---------------------------------------------------------------------------
// K4: loss = sum(ROW) / (2B)
// ---------------------------------------------------------------------------
__global__ __launch_bounds__(256) void final_kernel(const double* __restrict__ ROW,
                                                    float* __restrict__ out) {
  int t = threadIdx.x;
  double s = ROW[t] + ROW[t + 256];
  for (int off = 32; off > 0; off >>= 1) s += __shfl_down(s, off, 64);
  __shared__ double wsum[4];
  int wave = t >> 6, lane = t & 63;
  if (lane == 0) wsum[wave] = s;
  __syncthreads();
  if (t == 0) {
    double S = wsum[0] + wsum[1] + wsum[2] + wsum[3];
    out[0] = (float)(S / (double)N2);
  }
}

extern "C" void kernel_launch(void* const* d_in, const int* in_sizes, int n_in,
                              void* d_out, int out_size, void* d_ws, size_t ws_size,
                              hipStream_t stream) {
  const float* x1 = (const float*)d_in[0];  // [B, NX, 1, 1]
  const float* x2 = (const float*)d_in[1];  // [B, NX, 1, 1]
  const float* u  = (const float*)d_in[2];  // [B, NX, T]
  const float* dt = (const float*)d_in[3];  // [B]
  const float* dx = (const float*)d_in[4];  // [1]
  const float* vs = (const float*)d_in[5];  // [B, 3]
  char* ws = (char*)d_ws;
  float*  SIM = (float*)(ws + 0);          // 512*512*4 = 1 MB
  float*  A   = (float*)(ws + 1048576);    // 512*256*4 = 512 KB
  float*  C   = (float*)(ws + 1572864);    // 512 KB
  double* ROW = (double*)(ws + 2097152);   // 512*8 = 4 KB
  float* out = (float*)d_out;

  prep_kernel<<<BQ, 256, 0, stream>>>(x1, x2, u, dt, dx, vs, A, C);
  dim3 g2(N2 / TILE, N2 / TILE);
  dist_kernel<<<g2, 256, 0, stream>>>(A, C, SIM);
  row_kernel<<<N2, 256, 0, stream>>>(SIM, vs, ROW);
  final_kernel<<<1, 256, 0, stream>>>(ROW, out);
}